// Round 8
// baseline (26.217 us; speedup 1.0000x reference)
//
#include <hip/hip_runtime.h>
#include <math.h>

// Problem constants: B=256, N=64, M=64, d=32, TOPK=10
constexpr int Bn = 256;
constexpr int Nn = 64;
constexpr int Mn = 64;
constexpr int Dn = 32;
constexpr int TK = 10;
constexpr int NT = 1024;   // 16 waves
constexpr int PAD = 68;    // padded row stride (floats) for [.][64] tiles (b128-aligned, bank-spread)

// Correctly-rounded fp32 exp via fp64 (matches np within <=0.5 ulp)
__device__ __forceinline__ float exp_np(float x) {
    return (float)exp((double)x);
}
// Monotone fp32 -> uint32 order map (weights finite; no NaNs)
__device__ __forceinline__ unsigned int f2u(float f) {
    unsigned int b = __float_as_uint(f);
    return (b & 0x80000000u) ? ~b : (b | 0x80000000u);
}
__device__ __forceinline__ float u2f(unsigned int u) {
    return __uint_as_float((u & 0x80000000u) ? (u ^ 0x80000000u) : ~u);
}

__global__ __launch_bounds__(NT) void sparse_lambda_attn_kernel(
    const float* __restrict__ fv,   // [B,N,D]
    const float* __restrict__ cv,   // [B,M,D]
    const float* __restrict__ Wq,   // [D,D]
    const float* __restrict__ Wk,   // [D,D]
    const float* __restrict__ Wv,   // [D,M]
    float* __restrict__ out)        // [B, N*TK, D]
{
    // Replicate numpy fp32 semantics: NO fma contraction anywhere in this kernel.
    #pragma clang fp contract(off)

    __shared__ float f_lds[Nn][Dn];    // 8 KB (row-major, for output phase)
    __shared__ float c_lds[Mn][Dn];    // 8 KB
    __shared__ float fT[Dn][Nn];       // 8 KB (transposed, for lane-major phase A reads)
    __shared__ float cT[Dn][Mn];       // 8 KB
    __shared__ float KpT[Dn][PAD];     // 8.5 KB: [k][m] K logits -> K probs (transposed)
    __shared__ float QmT[Dn][PAD];     // 8.5 KB: [k][n] Q (transposed)
    __shared__ float Vw[Mn][PAD];      // 17 KB:  [m][v] V
    __shared__ float lamS[Dn][PAD];    // 8.5 KB: [k][v]
    __shared__ float Wt[Nn][PAD];      // 17 KB:  [n][v] weight
    __shared__ float colmax[Dn], colsum[Dn];
    __shared__ float topw[Nn][TK];     // 2.5 KB
    __shared__ int   topi[Nn][TK];     // 2.5 KB

    const int b    = blockIdx.x;
    const int tid  = threadIdx.x;
    const int lane = tid & 63;
    const int wid  = tid >> 6;

    // ---- stage: f,c -> LDS row-major AND transposed (coalesced f4 global reads) ----
    if (tid < 512) {
        const float4 v = reinterpret_cast<const float4*>(fv + (size_t)b * Nn * Dn)[tid];
        const int n = tid >> 3, d4 = (tid & 7) << 2;
        *reinterpret_cast<float4*>(&f_lds[n][d4]) = v;
        fT[d4 + 0][n] = v.x; fT[d4 + 1][n] = v.y; fT[d4 + 2][n] = v.z; fT[d4 + 3][n] = v.w;
    } else {
        const int t = tid - 512;
        const float4 v = reinterpret_cast<const float4*>(cv + (size_t)b * Mn * Dn)[t];
        const int m = t >> 3, d4 = (t & 7) << 2;
        *reinterpret_cast<float4*>(&c_lds[m][d4]) = v;
        cT[d4 + 0][m] = v.x; cT[d4 + 1][m] = v.y; cT[d4 + 2][m] = v.z; cT[d4 + 3][m] = v.w;
    }
    __syncthreads();

    // ---- Phase A: wave-owned column quads; W read via wave-uniform s_load (scalar cache).
    // Each output = sequential ascending-d mul-then-add, bit-identical to r7.
    if (wid < 8) {
        // wave w: K columns 4w..4w+3  AND  V columns 8w..8w+7; lane = m
        const int kq = __builtin_amdgcn_readfirstlane(wid);
        const int m = lane;
        const float* wkq = Wk + (kq << 2);   // + d*Dn per step
        const float* wvq = Wv + (kq << 3);   // + d*Mn per step
        float a0=0.f,a1=0.f,a2=0.f,a3=0.f;
        float b0=0.f,b1=0.f,b2=0.f,b3=0.f,b4=0.f,b5=0.f,b6=0.f,b7=0.f;
        #pragma unroll 4
        for (int d = 0; d < Dn; ++d) {
            const float cc = cT[d][m];
            const float* wr = wkq + d * Dn;
            const float* ur = wvq + d * Mn;
            const float w0 = wr[0], w1 = wr[1], w2 = wr[2], w3 = wr[3];
            const float u0 = ur[0], u1 = ur[1], u2 = ur[2], u3 = ur[3];
            const float u4 = ur[4], u5 = ur[5], u6 = ur[6], u7 = ur[7];
            a0 = a0 + cc * w0;  a1 = a1 + cc * w1;  a2 = a2 + cc * w2;  a3 = a3 + cc * w3;
            b0 = b0 + cc * u0;  b1 = b1 + cc * u1;  b2 = b2 + cc * u2;  b3 = b3 + cc * u3;
            b4 = b4 + cc * u4;  b5 = b5 + cc * u5;  b6 = b6 + cc * u6;  b7 = b7 + cc * u7;
        }
        // K logits, transposed store (stride-1 across lanes: conflict-free)
        KpT[(kq << 2) + 0][m] = a0;
        KpT[(kq << 2) + 1][m] = a1;
        KpT[(kq << 2) + 2][m] = a2;
        KpT[(kq << 2) + 3][m] = a3;
        // column max via shuffle tree (max is exactly order-independent)
        float m0=a0, m1=a1, m2=a2, m3=a3;
        #pragma unroll
        for (int off = 1; off < 64; off <<= 1) {
            m0 = fmaxf(m0, __shfl_xor(m0, off));
            m1 = fmaxf(m1, __shfl_xor(m1, off));
            m2 = fmaxf(m2, __shfl_xor(m2, off));
            m3 = fmaxf(m3, __shfl_xor(m3, off));
        }
        if (lane == 0) {
            colmax[(kq << 2) + 0] = m0;
            colmax[(kq << 2) + 1] = m1;
            colmax[(kq << 2) + 2] = m2;
            colmax[(kq << 2) + 3] = m3;
        }
        // V rows
        float4 r0; r0.x = b0; r0.y = b1; r0.z = b2; r0.w = b3;
        float4 r1; r1.x = b4; r1.y = b5; r1.z = b6; r1.w = b7;
        *reinterpret_cast<float4*>(&Vw[m][(kq << 3) + 0]) = r0;
        *reinterpret_cast<float4*>(&Vw[m][(kq << 3) + 4]) = r1;
    } else {
        // wave w-8: Q columns 4(w-8)..+3; lane = n
        const int qq = __builtin_amdgcn_readfirstlane(wid - 8);
        const int n = lane;
        const float* wqq = Wq + (qq << 2);
        float a0=0.f,a1=0.f,a2=0.f,a3=0.f;
        #pragma unroll 4
        for (int d = 0; d < Dn; ++d) {
            const float ff = fT[d][n];
            const float* wr = wqq + d * Dn;
            const float w0 = wr[0], w1 = wr[1], w2 = wr[2], w3 = wr[3];
            a0 = a0 + ff * w0;  a1 = a1 + ff * w1;  a2 = a2 + ff * w2;  a3 = a3 + ff * w3;
        }
        QmT[(qq << 2) + 0][n] = a0;
        QmT[(qq << 2) + 1][n] = a1;
        QmT[(qq << 2) + 2][n] = a2;
        QmT[(qq << 2) + 3][n] = a3;
    }
    __syncthreads();

    // ---- softmax over m per column k (np semantics; exp parallel, sum ascending-sequential) ----
    for (int i = tid; i < Dn * Mn; i += NT) {     // exp, parallel
        const int k = i >> 6, m = i & 63;
        KpT[k][m] = exp_np(KpT[k][m] - colmax[k]);
    }
    __syncthreads();
    if (tid < Dn) {                                // ascending-m sequential sum (np order)
        const int k = tid;
        float s = 0.f;
        for (int m = 0; m < Mn; ++m) s = s + KpT[k][m];
        colsum[k] = s;
    }
    __syncthreads();
    for (int i = tid; i < Dn * Mn; i += NT) {     // true division, parallel
        const int k = i >> 6, m = i & 63;
        KpT[k][m] = KpT[k][m] / colsum[k];
    }
    __syncthreads();

    // ---- lam[k][v] = sum_m K[m][k]*V[m][v]: 128 threads, (k4, v4) register block ----
    if (tid < 128) {
        const int kb = (tid >> 4) << 2;
        const int v4 = (tid & 15) << 2;
        float a00=0.f,a01=0.f,a02=0.f,a03=0.f;
        float a10=0.f,a11=0.f,a12=0.f,a13=0.f;
        float a20=0.f,a21=0.f,a22=0.f,a23=0.f;
        float a30=0.f,a31=0.f,a32=0.f,a33=0.f;
        for (int m = 0; m < Mn; ++m) {
            const float k0 = KpT[kb + 0][m];
            const float k1 = KpT[kb + 1][m];
            const float k2 = KpT[kb + 2][m];
            const float k3 = KpT[kb + 3][m];
            const float4 vv = *reinterpret_cast<const float4*>(&Vw[m][v4]);
            a00 = a00 + k0 * vv.x;  a01 = a01 + k0 * vv.y;  a02 = a02 + k0 * vv.z;  a03 = a03 + k0 * vv.w;
            a10 = a10 + k1 * vv.x;  a11 = a11 + k1 * vv.y;  a12 = a12 + k1 * vv.z;  a13 = a13 + k1 * vv.w;
            a20 = a20 + k2 * vv.x;  a21 = a21 + k2 * vv.y;  a22 = a22 + k2 * vv.z;  a23 = a23 + k2 * vv.w;
            a30 = a30 + k3 * vv.x;  a31 = a31 + k3 * vv.y;  a32 = a32 + k3 * vv.z;  a33 = a33 + k3 * vv.w;
        }
        float4 r;
        r.x=a00; r.y=a01; r.z=a02; r.w=a03; *reinterpret_cast<float4*>(&lamS[kb+0][v4]) = r;
        r.x=a10; r.y=a11; r.z=a12; r.w=a13; *reinterpret_cast<float4*>(&lamS[kb+1][v4]) = r;
        r.x=a20; r.y=a21; r.z=a22; r.w=a23; *reinterpret_cast<float4*>(&lamS[kb+2][v4]) = r;
        r.x=a30; r.y=a31; r.z=a32; r.w=a33; *reinterpret_cast<float4*>(&lamS[kb+3][v4]) = r;
    }
    __syncthreads();

    // ---- weight[n][v] = sum_k Q[n][k]*lam[k][v]: 256 threads, (n4, v4) register block ----
    if (tid < 256) {
        const int nb = (tid >> 4) << 2;
        const int v4 = (tid & 15) << 2;
        float a00=0.f,a01=0.f,a02=0.f,a03=0.f;
        float a10=0.f,a11=0.f,a12=0.f,a13=0.f;
        float a20=0.f,a21=0.f,a22=0.f,a23=0.f;
        float a30=0.f,a31=0.f,a32=0.f,a33=0.f;
        for (int k = 0; k < Dn; ++k) {
            const float q0 = QmT[k][nb + 0];
            const float q1 = QmT[k][nb + 1];
            const float q2 = QmT[k][nb + 2];
            const float q3 = QmT[k][nb + 3];
            const float4 lv = *reinterpret_cast<const float4*>(&lamS[k][v4]);
            a00 = a00 + q0 * lv.x;  a01 = a01 + q0 * lv.y;  a02 = a02 + q0 * lv.z;  a03 = a03 + q0 * lv.w;
            a10 = a10 + q1 * lv.x;  a11 = a11 + q1 * lv.y;  a12 = a12 + q1 * lv.z;  a13 = a13 + q1 * lv.w;
            a20 = a20 + q2 * lv.x;  a21 = a21 + q2 * lv.y;  a22 = a22 + q2 * lv.z;  a23 = a23 + q2 * lv.w;
            a30 = a30 + q3 * lv.x;  a31 = a31 + q3 * lv.y;  a32 = a32 + q3 * lv.z;  a33 = a33 + q3 * lv.w;
        }
        float4 r;
        r.x=a00; r.y=a01; r.z=a02; r.w=a03; *reinterpret_cast<float4*>(&Wt[nb+0][v4]) = r;
        r.x=a10; r.y=a11; r.z=a12; r.w=a13; *reinterpret_cast<float4*>(&Wt[nb+1][v4]) = r;
        r.x=a20; r.y=a21; r.z=a22; r.w=a23; *reinterpret_cast<float4*>(&Wt[nb+2][v4]) = r;
        r.x=a30; r.y=a31; r.z=a32; r.w=a33; *reinterpret_cast<float4*>(&Wt[nb+3][v4]) = r;
    }
    __syncthreads();

    // ---- top-10 per row: 16-lane group per row; comparison-only, bit-exact vs r7 ----
    {
        const int g = tid & 15;
        const int n = tid >> 4;

        const float4 s4 = *reinterpret_cast<const float4*>(&Wt[n][g << 2]);
        unsigned su0 = f2u(s4.x), su1 = f2u(s4.y), su2 = f2u(s4.z), su3 = f2u(s4.w);
        unsigned avail = 0xFu;

        float val0 = 0.f, myval = 0.f;
        int   myidx = 0;

        #pragma unroll
        for (int t = 0; t < TK; ++t) {
            unsigned bu = 0u; int bm = 64;
            if ((avail & 1u) && su0 > bu) { bu = su0; bm = (g << 2) + 0; }
            if ((avail & 2u) && su1 > bu) { bu = su1; bm = (g << 2) + 1; }
            if ((avail & 4u) && su2 > bu) { bu = su2; bm = (g << 2) + 2; }
            if ((avail & 8u) && su3 > bu) { bu = su3; bm = (g << 2) + 3; }
            #pragma unroll
            for (int off = 1; off <= 8; off <<= 1) {
                const unsigned ou = __shfl_xor(bu, off);
                const int      om = __shfl_xor(bm, off);
                if (ou > bu || (ou == bu && om < bm)) { bu = ou; bm = om; }
            }
            const float bv = u2f(bu);
            if (t == 0) val0 = bv;
            if (g == t) { myval = bv; myidx = bm; }
            if ((bm >> 2) == g) avail &= ~(1u << (bm & 3));
        }

        const float ev_own = (g < TK) ? exp_np(myval - val0) : 0.f;
        float s = 0.f;
        #pragma unroll
        for (int t = 0; t < TK; ++t) {
            const float e = __shfl(ev_own, (lane & 48) + t);
            s = s + e;
        }
        if (g < TK) {
            topw[n][g] = ev_own / s;
            topi[n][g] = myidx;
        }
    }
    __syncthreads();

    // ---- output: out[b][n*TK+t][d] = w * (f[n][d]*c[idx][d]), float4 coalesced ----
    float* ob = out + (size_t)b * (Nn * TK * Dn);
    constexpr int TOT4 = Nn * TK * Dn / 4;   // 5120 float4 per batch
    for (int i = tid; i < TOT4; i += NT) {
        const int n = i / (TK * Dn / 4);            // / 80
        const int r = i - n * (TK * Dn / 4);
        const int t = r >> 3;
        const int d4 = r & 7;
        const float w = topw[n][t];
        const int m = topi[n][t];
        const float4 f4 = reinterpret_cast<const float4*>(&f_lds[n][0])[d4];
        const float4 c4 = reinterpret_cast<const float4*>(&c_lds[m][0])[d4];
        float4 o;
        { const float vx = f4.x * c4.x; o.x = w * vx; }
        { const float vy = f4.y * c4.y; o.y = w * vy; }
        { const float vz = f4.z * c4.z; o.z = w * vz; }
        { const float vw = f4.w * c4.w; o.w = w * vw; }
        reinterpret_cast<float4*>(ob)[i] = o;
    }
}

extern "C" void kernel_launch(void* const* d_in, const int* in_sizes, int n_in,
                              void* d_out, int out_size, void* d_ws, size_t ws_size,
                              hipStream_t stream) {
    const float* fv = (const float*)d_in[0];   // featureVec [256,64,32]
    const float* cv = (const float*)d_in[1];   // contextVec [256,64,32]
    const float* Wq = (const float*)d_in[2];   // [32,32]
    const float* Wk = (const float*)d_in[3];   // [32,32]
    const float* Wv = (const float*)d_in[4];   // [32,64]
    float* out = (float*)d_out;                // [256, 640, 32]

    sparse_lambda_attn_kernel<<<Bn, NT, 0, stream>>>(fv, cv, Wq, Wk, Wv, out);
}